// Round 1
// baseline (1105.035 us; speedup 1.0000x reference)
//
#include <hip/hip_runtime.h>

#define N_NODES 100000
#define N_EDGES 3200000
#define F_IN 512
#define NH 16
#define F_OUT 128
#define NCLS 3

#define NB 782        // ceil(100000/128) buckets of 128 nodes (key = dst>>7)
#define BCAP 4736     // mean 4092 + ~10 sigma
#define CHUNK 16384   // edges per binning block
#define NBIN 196      // ceil(N_EDGES/CHUNK)
#define GEMM_BLOCKS 1250

typedef float  f32x4 __attribute__((ext_vector_type(4)));
typedef short  s16x8 __attribute__((ext_vector_type(8)));
typedef unsigned short u16x4 __attribute__((ext_vector_type(4)));

static __device__ __forceinline__ unsigned short f2bf(float f) {
    union { float f; unsigned u; } v; v.f = f;
    unsigned r = v.u + 0x7FFFu + ((v.u >> 16) & 1u);   // RNE
    return (unsigned short)(r >> 16);
}
static __device__ __forceinline__ float bf2f(unsigned short u) {
    union { unsigned u; float f; } v; v.u = ((unsigned)u) << 16;
    return v.f;
}

// ---------------- W1 -> bf16 B-fragment pack ----------------
__global__ void w1b_prep_kernel(const float* __restrict__ W1, unsigned short* __restrict__ W1B) {
    int idx = blockIdx.x * blockDim.x + threadIdx.x;
    if (idx >= 16 * 64 * 8) return;
    int kc = idx >> 9, lane = (idx >> 3) & 63, i = idx & 7;
    int k = kc * 32 + (lane >> 4) * 8 + i;
    int j = lane & 15;
    W1B[idx] = f2bf(W1[k * NH + j]);
}

// ---------------- Wc = W2 @ Wfc (16x3), bc = b2 @ Wfc + bfc (3) ----------------
__global__ void wc_prep_kernel(const float* __restrict__ W2, const float* __restrict__ b2,
                               const float* __restrict__ Wfc, const float* __restrict__ bfc,
                               float* __restrict__ Wc) {
    int t = threadIdx.x;
    if (t < NH * NCLS) {
        int j = t / NCLS, c = t % NCLS;
        float acc = 0.0f;
        for (int k = 0; k < F_OUT; ++k) acc += W2[j * F_OUT + k] * Wfc[k * NCLS + c];
        Wc[t] = acc;
    } else if (t < NH * NCLS + NCLS) {
        int c = t - NH * NCLS;
        float acc = bfc[c];
        for (int k = 0; k < F_OUT; ++k) acc += b2[k] * Wfc[k * NCLS + c];
        Wc[t] = acc;
    }
}

// ---------------- FUSED: blocks [0,NBIN) bin edges; [NBIN, NBIN+GEMM_BLOCKS) GEMM1 ----------------
// GEMM1 writes h1raw = bf16(feat @ W1) WITHOUT norm_src (applied per-edge in aggA),
// which removes the deg_out dependency and lets binning hide under the 205 MB feat read.
__global__ __launch_bounds__(256) void fused_bin_gemm(const int* __restrict__ src,
                                                      const int* __restrict__ dst,
                                                      int* __restrict__ deg_out,
                                                      int* __restrict__ gcursor,
                                                      int* __restrict__ pairbuf,
                                                      const float* __restrict__ feat,
                                                      const unsigned short* __restrict__ W1B,
                                                      unsigned short* __restrict__ h1b) {
    __shared__ int hist[NB];
    __shared__ int cur[NB];
    int t = threadIdx.x;
    if (blockIdx.x < NBIN) {
        for (int i = t; i < NB; i += 256) hist[i] = 0;
        __syncthreads();
        int e0 = blockIdx.x * CHUNK;
        int nE = N_EDGES - e0; if (nE > CHUNK) nE = CHUNK;   // always multiple of 4
        for (int i = 4 * t; i < nE; i += 1024) {
            int4 sv = *(const int4*)(src + e0 + i);
            int4 dv = *(const int4*)(dst + e0 + i);
            atomicAdd(&deg_out[sv.x], 1); atomicAdd(&deg_out[sv.y], 1);
            atomicAdd(&deg_out[sv.z], 1); atomicAdd(&deg_out[sv.w], 1);
            atomicAdd(&hist[dv.x >> 7], 1); atomicAdd(&hist[dv.y >> 7], 1);
            atomicAdd(&hist[dv.z >> 7], 1); atomicAdd(&hist[dv.w >> 7], 1);
        }
        __syncthreads();
        int rot = blockIdx.x % NB;
        for (int j = t; j < NB; j += 256) {
            int b = j + rot; if (b >= NB) b -= NB;
            int h = hist[b];
            cur[b] = (h > 0) ? atomicAdd(&gcursor[b], h) : 0;
        }
        __syncthreads();
        for (int i = 4 * t; i < nE; i += 1024) {
            int4 sv = *(const int4*)(src + e0 + i);
            int4 dv = *(const int4*)(dst + e0 + i);
            int ss[4] = {sv.x, sv.y, sv.z, sv.w};
            int dd[4] = {dv.x, dv.y, dv.z, dv.w};
#pragma unroll
            for (int k = 0; k < 4; ++k) {
                int bb = dd[k] >> 7;
                int pos = atomicAdd(&cur[bb], 1);
                if (pos < BCAP) pairbuf[bb * BCAP + pos] = ss[k] | ((dd[k] & 127) << 17);
            }
        }
    } else {
        int lane = t & 63;
        int m = lane & 15;
        int q = lane >> 4;
        const s16x8* wb = (const s16x8*)W1B;
        s16x8 B[16];
#pragma unroll
        for (int kc = 0; kc < 16; ++kc) B[kc] = wb[kc * 64 + lane];
        int w = (blockIdx.x - NBIN) * 4 + (t >> 6);
        int nwaves = GEMM_BLOCKS * 4;
        const int ntiles = N_NODES / 16;   // 6250
        for (int tile = w; tile < ntiles; tile += nwaves) {
            f32x4 acc = {0.0f, 0.0f, 0.0f, 0.0f};
            const float* arow = feat + (size_t)(tile * 16 + m) * F_IN + q * 8;
#pragma unroll
            for (int kc = 0; kc < 16; ++kc) {
                f32x4 fa = *(const f32x4*)(arow + kc * 32);
                f32x4 fb = *(const f32x4*)(arow + kc * 32 + 4);
                s16x8 a;
                a[0] = f2bf(fa.x); a[1] = f2bf(fa.y); a[2] = f2bf(fa.z); a[3] = f2bf(fa.w);
                a[4] = f2bf(fb.x); a[5] = f2bf(fb.y); a[6] = f2bf(fb.z); a[7] = f2bf(fb.w);
                acc = __builtin_amdgcn_mfma_f32_16x16x32_bf16(a, B[kc], acc, 0, 0, 0);
            }
#pragma unroll
            for (int r = 0; r < 4; ++r) {
                int node = tile * 16 + q * 4 + r;
                h1b[(size_t)node * NH + m] = f2bf(acc[r]);
            }
        }
    }
}

// ---------------- aggA: per dst-bucket LDS scatter-add of ns[s]*h1raw[s] ----------------
// x1nb = bf16(relu(nd * sum + b1) * ns[n]); also counts deg_in -> norm_dst.
// LDS layout [128][17] f32 (stride 17 breaks power-of-2 bank aliasing).
__global__ __launch_bounds__(256) void aggA_kernel(const int* __restrict__ gcursor,
                                                   const int* __restrict__ pairbuf,
                                                   const unsigned short* __restrict__ h1b,
                                                   const int* __restrict__ deg_out,
                                                   const float* __restrict__ b1,
                                                   unsigned short* __restrict__ x1nb,
                                                   float* __restrict__ norm_dst) {
    __shared__ float accS[128 * 17];
    int b = blockIdx.x;
    int t = threadIdx.x;
    for (int i = t; i < 128 * 17; i += 256) accS[i] = 0.0f;
    __syncthreads();
    int c = gcursor[b]; if (c > BCAP) c = BCAP;
    const int* pb = pairbuf + (size_t)b * BCAP;
    int g = t >> 2, comp = t & 3;
    for (int i = g; i < c; i += 64) {
        int pv = pb[i];
        int s = pv & 0x1FFFF;
        int node = pv >> 17;
        float ns = rsqrtf(fmaxf((float)deg_out[s], 1.0f));
        u16x4 hv = *(const u16x4*)(h1b + (size_t)s * NH + comp * 4);
        float* ap = accS + node * 17 + comp * 4;
        atomicAdd(ap + 0, ns * bf2f(hv.x));
        atomicAdd(ap + 1, ns * bf2f(hv.y));
        atomicAdd(ap + 2, ns * bf2f(hv.z));
        atomicAdd(ap + 3, ns * bf2f(hv.w));
        if (comp == 0) atomicAdd(accS + node * 17 + 16, 1.0f);
    }
    __syncthreads();
    int node = b * 128 + t;
    if (t < 128 && node < N_NODES) {
        float cnt = accS[t * 17 + 16];
        float nd = rsqrtf(fmaxf(cnt, 1.0f));
        float nsn = rsqrtf(fmaxf((float)deg_out[node], 1.0f));
        s16x8 o0, o1;
#pragma unroll
        for (int j = 0; j < 8; ++j) {
            float v = fmaxf(accS[t * 17 + j] * nd + b1[j], 0.0f) * nsn;
            o0[j] = (short)f2bf(v);
        }
#pragma unroll
        for (int j = 0; j < 8; ++j) {
            float v = fmaxf(accS[t * 17 + 8 + j] * nd + b1[8 + j], 0.0f) * nsn;
            o1[j] = (short)f2bf(v);
        }
        *(s16x8*)(x1nb + (size_t)node * NH) = o0;
        *(s16x8*)(x1nb + (size_t)node * NH + 8) = o1;
        norm_dst[node] = nd;
    }
}

// ---------------- aggB: per dst-bucket LDS scatter-add of x1n[s]; out = nd*(sum@Wc)+bc ----------------
__global__ __launch_bounds__(256) void aggB_kernel(const int* __restrict__ gcursor,
                                                   const int* __restrict__ pairbuf,
                                                   const unsigned short* __restrict__ x1nb,
                                                   const float* __restrict__ norm_dst,
                                                   const float* __restrict__ Wc,
                                                   float* __restrict__ out) {
    __shared__ float accS[128 * 17];
    __shared__ float Wcs[NH * NCLS + NCLS];
    int b = blockIdx.x;
    int t = threadIdx.x;
    if (t < NH * NCLS + NCLS) Wcs[t] = Wc[t];
    for (int i = t; i < 128 * 17; i += 256) accS[i] = 0.0f;
    __syncthreads();
    int c = gcursor[b]; if (c > BCAP) c = BCAP;
    const int* pb = pairbuf + (size_t)b * BCAP;
    int g = t >> 2, comp = t & 3;
    for (int i = g; i < c; i += 64) {
        int pv = pb[i];
        int s = pv & 0x1FFFF;
        int node = pv >> 17;
        u16x4 hv = *(const u16x4*)(x1nb + (size_t)s * NH + comp * 4);
        float* ap = accS + node * 17 + comp * 4;
        atomicAdd(ap + 0, bf2f(hv.x));
        atomicAdd(ap + 1, bf2f(hv.y));
        atomicAdd(ap + 2, bf2f(hv.z));
        atomicAdd(ap + 3, bf2f(hv.w));
    }
    __syncthreads();
    int node = b * 128 + t;
    if (t < 128 && node < N_NODES) {
        float nd = norm_dst[node];
        float p0 = 0.0f, p1 = 0.0f, p2 = 0.0f;
#pragma unroll
        for (int j = 0; j < NH; ++j) {
            float y = accS[t * 17 + j];
            p0 += y * Wcs[j * NCLS + 0];
            p1 += y * Wcs[j * NCLS + 1];
            p2 += y * Wcs[j * NCLS + 2];
        }
        out[(size_t)node * NCLS + 0] = nd * p0 + Wcs[NH * NCLS + 0];
        out[(size_t)node * NCLS + 1] = nd * p1 + Wcs[NH * NCLS + 1];
        out[(size_t)node * NCLS + 2] = nd * p2 + Wcs[NH * NCLS + 2];
    }
}

// ---------------- launch ----------------
extern "C" void kernel_launch(void* const* d_in, const int* in_sizes, int n_in,
                              void* d_out, int out_size, void* d_ws, size_t ws_size,
                              hipStream_t stream) {
    const float* feat = (const float*)d_in[0];
    const int*   src  = (const int*)d_in[1];
    const int*   dst  = (const int*)d_in[2];
    const float* W1   = (const float*)d_in[3];
    const float* b1   = (const float*)d_in[4];
    const float* W2   = (const float*)d_in[5];
    const float* b2   = (const float*)d_in[6];
    const float* Wfc  = (const float*)d_in[7];
    const float* bfc  = (const float*)d_in[8];
    float* out = (float*)d_out;

    char* ws = (char*)d_ws;
    size_t off = 0;
    auto carve = [&](size_t bytes) {
        char* p = ws + off;
        off = (off + bytes + 255) & ~(size_t)255;
        return p;
    };
    int*   deg_out  = (int*)carve((size_t)N_NODES * 4);
    int*   gcursor  = (int*)carve((size_t)NB * 4);
    int*   pairbuf  = (int*)carve((size_t)NB * BCAP * 4);
    float* norm_dst = (float*)carve((size_t)N_NODES * 4);
    unsigned short* h1b  = (unsigned short*)carve((size_t)N_NODES * NH * 2);
    unsigned short* x1nb = (unsigned short*)carve((size_t)N_NODES * NH * 2);
    unsigned short* W1B  = (unsigned short*)carve(16 * 64 * 8 * 2);
    float* Wc       = (float*)carve((NH * NCLS + NCLS) * 4);
    (void)ws_size;

    hipMemsetAsync(deg_out, 0, (size_t)N_NODES * 4, stream);
    hipMemsetAsync(gcursor, 0, (size_t)NB * 4, stream);

    w1b_prep_kernel<<<32, 256, 0, stream>>>(W1, W1B);
    wc_prep_kernel<<<1, 64, 0, stream>>>(W2, b2, Wfc, bfc, Wc);

    fused_bin_gemm<<<NBIN + GEMM_BLOCKS, 256, 0, stream>>>(src, dst, deg_out, gcursor,
                                                           pairbuf, feat, W1B, h1b);

    aggA_kernel<<<NB, 256, 0, stream>>>(gcursor, pairbuf, h1b, deg_out, b1, x1nb, norm_dst);

    aggB_kernel<<<NB, 256, 0, stream>>>(gcursor, pairbuf, x1nb, norm_dst, Wc, out);
}

// Round 3
// 537.089 us; speedup vs baseline: 2.0575x; 2.0575x over previous
//
#include <hip/hip_runtime.h>

#define N_NODES 100000
#define N_EDGES 3200000
#define F_IN 512
#define NH 16
#define F_OUT 128
#define NCLS 3

#define NB 782        // ceil(100000/128) buckets of 128 nodes (key = dst>>7)
#define BCAP 4736     // mean 4092 + ~10 sigma
#define CHUNK 16384   // edges per binning block
#define NBIN 196      // ceil(N_EDGES/CHUNK)
#define GEMM_BLOCKS 1250

typedef float  f32x4 __attribute__((ext_vector_type(4)));
typedef short  s16x8 __attribute__((ext_vector_type(8)));
typedef unsigned short u16x8 __attribute__((ext_vector_type(8)));

static __device__ __forceinline__ unsigned short f2bf(float f) {
    union { float f; unsigned u; } v; v.f = f;
    unsigned r = v.u + 0x7FFFu + ((v.u >> 16) & 1u);   // RNE
    return (unsigned short)(r >> 16);
}
static __device__ __forceinline__ float bf2f(unsigned short u) {
    union { unsigned u; float f; } v; v.u = ((unsigned)u) << 16;
    return v.f;
}

// ---------------- W1 -> bf16 B-fragment pack ----------------
__global__ void w1b_prep_kernel(const float* __restrict__ W1, unsigned short* __restrict__ W1B) {
    int idx = blockIdx.x * blockDim.x + threadIdx.x;
    if (idx >= 16 * 64 * 8) return;
    int kc = idx >> 9, lane = (idx >> 3) & 63, i = idx & 7;
    int k = kc * 32 + (lane >> 4) * 8 + i;
    int j = lane & 15;
    W1B[idx] = f2bf(W1[k * NH + j]);
}

// ---------------- Wc = W2 @ Wfc (16x3), bc = b2 @ Wfc + bfc (3) ----------------
__global__ void wc_prep_kernel(const float* __restrict__ W2, const float* __restrict__ b2,
                               const float* __restrict__ Wfc, const float* __restrict__ bfc,
                               float* __restrict__ Wc) {
    int t = threadIdx.x;
    if (t < NH * NCLS) {
        int j = t / NCLS, c = t % NCLS;
        float acc = 0.0f;
        for (int k = 0; k < F_OUT; ++k) acc += W2[j * F_OUT + k] * Wfc[k * NCLS + c];
        Wc[t] = acc;
    } else if (t < NH * NCLS + NCLS) {
        int c = t - NH * NCLS;
        float acc = bfc[c];
        for (int k = 0; k < F_OUT; ++k) acc += b2[k] * Wfc[k * NCLS + c];
        Wc[t] = acc;
    }
}

// ---------------- FUSED: blocks [0,NBIN) bin edges; [NBIN, NBIN+GEMM_BLOCKS) GEMM1 ----------------
// GEMM1 writes h1raw = bf16(feat @ W1) WITHOUT norm_src (applied per-edge in agg1),
// which removes the deg_out dependency and lets binning hide under the 205 MB feat read.
__global__ __launch_bounds__(256) void fused_bin_gemm(const int* __restrict__ src,
                                                      const int* __restrict__ dst,
                                                      int* __restrict__ deg_out,
                                                      int* __restrict__ gcursor,
                                                      int* __restrict__ pairbuf,
                                                      const float* __restrict__ feat,
                                                      const unsigned short* __restrict__ W1B,
                                                      unsigned short* __restrict__ h1b) {
    __shared__ int hist[NB];
    __shared__ int cur[NB];
    int t = threadIdx.x;
    if (blockIdx.x < NBIN) {
        for (int i = t; i < NB; i += 256) hist[i] = 0;
        __syncthreads();
        int e0 = blockIdx.x * CHUNK;
        int nE = N_EDGES - e0; if (nE > CHUNK) nE = CHUNK;   // always multiple of 4
        for (int i = 4 * t; i < nE; i += 1024) {
            int4 sv = *(const int4*)(src + e0 + i);
            int4 dv = *(const int4*)(dst + e0 + i);
            atomicAdd(&deg_out[sv.x], 1); atomicAdd(&deg_out[sv.y], 1);
            atomicAdd(&deg_out[sv.z], 1); atomicAdd(&deg_out[sv.w], 1);
            atomicAdd(&hist[dv.x >> 7], 1); atomicAdd(&hist[dv.y >> 7], 1);
            atomicAdd(&hist[dv.z >> 7], 1); atomicAdd(&hist[dv.w >> 7], 1);
        }
        __syncthreads();
        int rot = blockIdx.x % NB;
        for (int j = t; j < NB; j += 256) {
            int b = j + rot; if (b >= NB) b -= NB;
            int h = hist[b];
            cur[b] = (h > 0) ? atomicAdd(&gcursor[b], h) : 0;
        }
        __syncthreads();
        for (int i = 4 * t; i < nE; i += 1024) {
            int4 sv = *(const int4*)(src + e0 + i);
            int4 dv = *(const int4*)(dst + e0 + i);
            int ss[4] = {sv.x, sv.y, sv.z, sv.w};
            int dd[4] = {dv.x, dv.y, dv.z, dv.w};
#pragma unroll
            for (int k = 0; k < 4; ++k) {
                int bb = dd[k] >> 7;
                int pos = atomicAdd(&cur[bb], 1);
                if (pos < BCAP) pairbuf[bb * BCAP + pos] = ss[k] | ((dd[k] & 127) << 17);
            }
        }
    } else {
        int lane = t & 63;
        int m = lane & 15;
        int q = lane >> 4;
        const s16x8* wb = (const s16x8*)W1B;
        s16x8 B[16];
#pragma unroll
        for (int kc = 0; kc < 16; ++kc) B[kc] = wb[kc * 64 + lane];
        int w = (blockIdx.x - NBIN) * 4 + (t >> 6);
        int nwaves = GEMM_BLOCKS * 4;
        const int ntiles = N_NODES / 16;   // 6250
        for (int tile = w; tile < ntiles; tile += nwaves) {
            f32x4 acc = {0.0f, 0.0f, 0.0f, 0.0f};
            const float* arow = feat + (size_t)(tile * 16 + m) * F_IN + q * 8;
#pragma unroll
            for (int kc = 0; kc < 16; ++kc) {
                f32x4 fa = *(const f32x4*)(arow + kc * 32);
                f32x4 fb = *(const f32x4*)(arow + kc * 32 + 4);
                s16x8 a;
                a[0] = f2bf(fa.x); a[1] = f2bf(fa.y); a[2] = f2bf(fa.z); a[3] = f2bf(fa.w);
                a[4] = f2bf(fb.x); a[5] = f2bf(fb.y); a[6] = f2bf(fb.z); a[7] = f2bf(fb.w);
                acc = __builtin_amdgcn_mfma_f32_16x16x32_bf16(a, B[kc], acc, 0, 0, 0);
            }
#pragma unroll
            for (int r = 0; r < 4; ++r) {
                int node = tile * 16 + q * 4 + r;
                h1b[(size_t)node * NH + m] = f2bf(acc[r]);
            }
        }
    }
}

// ---------------- exclusive scan over bucket counts -> csr bucket bases ----------------
__global__ __launch_bounds__(1024) void bucket_scan_kernel(const int* __restrict__ gcursor,
                                                           int* __restrict__ csr_base) {
    __shared__ int s[1024];
    int t = threadIdx.x;
    int v = 0;
    if (t < NB) { v = gcursor[t]; if (v > BCAP) v = BCAP; }
    s[t] = v;
    __syncthreads();
    for (int off = 1; off < 1024; off <<= 1) {
        int x = (t >= off) ? s[t - off] : 0;
        __syncthreads();
        s[t] += x;
        __syncthreads();
    }
    if (t < NB) csr_base[t] = s[t] - v;
}

// ---------------- per-bucket CSR build + row_ptr + norm_dst + norm_src ----------------
__global__ __launch_bounds__(256) void bucket_csr_kernel(const int* __restrict__ gcursor,
                                                         const int* __restrict__ csr_base,
                                                         const int* __restrict__ pairbuf,
                                                         const int* __restrict__ deg_out,
                                                         int* __restrict__ col,
                                                         int* __restrict__ row_ptr,
                                                         float* __restrict__ norm_dst,
                                                         float* __restrict__ norm_src) {
    __shared__ int hist[128];
    __shared__ int scn[128];
    int b = blockIdx.x;
    int t = threadIdx.x;
    if (t < 128) hist[t] = 0;
    __syncthreads();
    int c = gcursor[b]; if (c > BCAP) c = BCAP;
    const int* pb = pairbuf + (size_t)b * BCAP;
    int pk[19], rk[19];
#pragma unroll
    for (int it = 0; it < 19; ++it) {
        int i = t + it * 256;
        bool valid = i < c;
        int v = valid ? pb[i] : 0;
        pk[it] = v;
        rk[it] = valid ? atomicAdd(&hist[v >> 17], 1) : 0;
    }
    __syncthreads();
    if (t < 128) scn[t] = hist[t];
    __syncthreads();
    for (int off = 1; off < 128; off <<= 1) {
        int x = (t >= off && t < 128) ? scn[t - off] : 0;
        __syncthreads();
        if (t < 128) scn[t] += x;   // inclusive
        __syncthreads();
    }
    int gbase = csr_base[b];
#pragma unroll
    for (int it = 0; it < 19; ++it) {
        int i = t + it * 256;
        if (i < c) {
            int v = pk[it];
            int node = v >> 17;
            int pos = gbase + (scn[node] - hist[node]) + rk[it];
            col[pos] = v & 0x1FFFF;
        }
    }
    int node = b * 128 + t;
    if (t < 128 && node < N_NODES) {
        row_ptr[node] = gbase + scn[t] - hist[t];
        norm_dst[node] = rsqrtf(fmaxf((float)hist[t], 1.0f));
        norm_src[node] = rsqrtf(fmaxf((float)deg_out[node], 1.0f));
    }
    if (b == NB - 1 && t == 0) row_ptr[N_NODES] = N_EDGES;
}

// ---------------- AGG1: x1nb = bf16(relu(nd * sum ns[s]*h1raw[src] + b1) * ns[n]) ----------------
// wave-per-node; 2 lanes x ushort8(16B) per edge row, 32 edges in flight.
__global__ __launch_bounds__(256) void agg1_kernel(const int* __restrict__ row_ptr,
                                                   const int* __restrict__ col,
                                                   const unsigned short* __restrict__ h1b,
                                                   const float* __restrict__ norm_dst,
                                                   const float* __restrict__ norm_src,
                                                   const float* __restrict__ b1,
                                                   unsigned short* __restrict__ x1nb) {
    int t = threadIdx.x;
    int lane = t & 63;
    int n = blockIdx.x * 4 + (t >> 6);
    int eo = lane >> 1, half = lane & 1;
    int beg = row_ptr[n], end = row_ptr[n + 1];
    float acc[8] = {0.0f, 0.0f, 0.0f, 0.0f, 0.0f, 0.0f, 0.0f, 0.0f};
    for (int e = beg + eo; e < end; e += 32) {
        int s = col[e];
        float ns = norm_src[s];                       // 2 lanes same addr -> broadcast
        u16x8 hv = *(const u16x8*)(h1b + (size_t)s * NH + half * 8);
#pragma unroll
        for (int j = 0; j < 8; ++j) acc[j] += ns * bf2f(hv[j]);
    }
#pragma unroll
    for (int sh = 2; sh <= 32; sh <<= 1) {
#pragma unroll
        for (int j = 0; j < 8; ++j) acc[j] += __shfl_xor(acc[j], sh);
    }
    if (lane < 2) {
        float nd = norm_dst[n];
        float nsn = norm_src[n];
        u16x8 o;
#pragma unroll
        for (int j = 0; j < 8; ++j) {
            float v = acc[j] * nd + b1[half * 8 + j];
            o[j] = f2bf(fmaxf(v, 0.0f) * nsn);
        }
        *(u16x8*)(x1nb + (size_t)n * NH + half * 8) = o;
    }
}

// ---------------- AGG2 + tail: out = nd * (sum x1n[src]) @ Wc + bc ----------------
__global__ __launch_bounds__(256) void agg2_kernel(const int* __restrict__ row_ptr,
                                                   const int* __restrict__ col,
                                                   const unsigned short* __restrict__ x1nb,
                                                   const float* __restrict__ norm_dst,
                                                   const float* __restrict__ Wc,
                                                   float* __restrict__ out) {
    __shared__ float Wcs[NH * NCLS + NCLS];
    int t = threadIdx.x;
    if (t < NH * NCLS + NCLS) Wcs[t] = Wc[t];
    __syncthreads();
    int lane = t & 63;
    int n = blockIdx.x * 4 + (t >> 6);
    int eo = lane >> 1, half = lane & 1;
    int beg = row_ptr[n], end = row_ptr[n + 1];
    float acc[8] = {0.0f, 0.0f, 0.0f, 0.0f, 0.0f, 0.0f, 0.0f, 0.0f};
    for (int e = beg + eo; e < end; e += 32) {
        int s = col[e];
        u16x8 hv = *(const u16x8*)(x1nb + (size_t)s * NH + half * 8);
#pragma unroll
        for (int j = 0; j < 8; ++j) acc[j] += bf2f(hv[j]);
    }
#pragma unroll
    for (int sh = 2; sh <= 32; sh <<= 1) {
#pragma unroll
        for (int j = 0; j < 8; ++j) acc[j] += __shfl_xor(acc[j], sh);
    }
    float p0 = 0.0f, p1 = 0.0f, p2 = 0.0f;
    if (lane < 2) {
#pragma unroll
        for (int j = 0; j < 8; ++j) {
            float y = acc[j];
            int jj = half * 8 + j;
            p0 += y * Wcs[jj * NCLS + 0];
            p1 += y * Wcs[jj * NCLS + 1];
            p2 += y * Wcs[jj * NCLS + 2];
        }
    }
    p0 += __shfl_xor(p0, 1);
    p1 += __shfl_xor(p1, 1);
    p2 += __shfl_xor(p2, 1);
    if (lane == 0) {
        float nd = norm_dst[n];
        out[(size_t)n * NCLS + 0] = nd * p0 + Wcs[NH * NCLS + 0];
        out[(size_t)n * NCLS + 1] = nd * p1 + Wcs[NH * NCLS + 1];
        out[(size_t)n * NCLS + 2] = nd * p2 + Wcs[NH * NCLS + 2];
    }
}

// ---------------- launch ----------------
extern "C" void kernel_launch(void* const* d_in, const int* in_sizes, int n_in,
                              void* d_out, int out_size, void* d_ws, size_t ws_size,
                              hipStream_t stream) {
    const float* feat = (const float*)d_in[0];
    const int*   src  = (const int*)d_in[1];
    const int*   dst  = (const int*)d_in[2];
    const float* W1   = (const float*)d_in[3];
    const float* b1   = (const float*)d_in[4];
    const float* W2   = (const float*)d_in[5];
    const float* b2   = (const float*)d_in[6];
    const float* Wfc  = (const float*)d_in[7];
    const float* bfc  = (const float*)d_in[8];
    float* out = (float*)d_out;

    char* ws = (char*)d_ws;
    size_t off = 0;
    auto carve = [&](size_t bytes) {
        char* p = ws + off;
        off = (off + bytes + 255) & ~(size_t)255;
        return p;
    };
    int*   deg_out  = (int*)carve((size_t)N_NODES * 4);
    int*   gcursor  = (int*)carve((size_t)NB * 4);
    int*   csr_base = (int*)carve((size_t)NB * 4);
    int*   pairbuf  = (int*)carve((size_t)NB * BCAP * 4);
    int*   row_ptr  = (int*)carve((size_t)(N_NODES + 1) * 4);
    int*   col      = (int*)carve((size_t)N_EDGES * 4);
    float* norm_dst = (float*)carve((size_t)N_NODES * 4);
    float* norm_src = (float*)carve((size_t)N_NODES * 4);
    unsigned short* h1b  = (unsigned short*)carve((size_t)N_NODES * NH * 2);
    unsigned short* x1nb = (unsigned short*)carve((size_t)N_NODES * NH * 2);
    unsigned short* W1B  = (unsigned short*)carve(16 * 64 * 8 * 2);
    float* Wc       = (float*)carve((NH * NCLS + NCLS) * 4);
    (void)ws_size;

    hipMemsetAsync(deg_out, 0, (size_t)N_NODES * 4, stream);
    hipMemsetAsync(gcursor, 0, (size_t)NB * 4, stream);

    w1b_prep_kernel<<<32, 256, 0, stream>>>(W1, W1B);
    wc_prep_kernel<<<1, 64, 0, stream>>>(W2, b2, Wfc, bfc, Wc);

    fused_bin_gemm<<<NBIN + GEMM_BLOCKS, 256, 0, stream>>>(src, dst, deg_out, gcursor,
                                                           pairbuf, feat, W1B, h1b);

    bucket_scan_kernel<<<1, 1024, 0, stream>>>(gcursor, csr_base);
    bucket_csr_kernel<<<NB, 256, 0, stream>>>(gcursor, csr_base, pairbuf, deg_out,
                                              col, row_ptr, norm_dst, norm_src);

    agg1_kernel<<<N_NODES / 4, 256, 0, stream>>>(row_ptr, col, h1b, norm_dst, norm_src, b1, x1nb);

    agg2_kernel<<<N_NODES / 4, 256, 0, stream>>>(row_ptr, col, x1nb, norm_dst, Wc, out);
}

// Round 8
// 531.443 us; speedup vs baseline: 2.0793x; 1.0106x over previous
//
#include <hip/hip_runtime.h>

#define N_NODES 100000
#define N_EDGES 3200000
#define F_IN 512
#define NH 16
#define F_OUT 128
#define NCLS 3

#define NB 782        // ceil(100000/128) buckets of 128 nodes (key = dst>>7)
#define BCAP 4736     // mean 4092 + ~10 sigma
#define CHUNK 16384   // edges per binning block
#define NBIN 196      // ceil(N_EDGES/CHUNK)
#define GEMM_BLOCKS 1250

typedef float  f32x4 __attribute__((ext_vector_type(4)));
typedef short  s16x8 __attribute__((ext_vector_type(8)));
typedef unsigned short u16x8 __attribute__((ext_vector_type(8)));

static __device__ __forceinline__ unsigned short f2bf(float f) {
    union { float f; unsigned u; } v; v.f = f;
    unsigned r = v.u + 0x7FFFu + ((v.u >> 16) & 1u);   // RNE
    return (unsigned short)(r >> 16);
}
static __device__ __forceinline__ float bf2f(unsigned short u) {
    union { unsigned u; float f; } v; v.u = ((unsigned)u) << 16;
    return v.f;
}

// ---------------- merged prep: blocks 0-31 pack W1 -> bf16 B-frags; block 32 Wc ----------------
__global__ void prep_kernel(const float* __restrict__ W1, unsigned short* __restrict__ W1B,
                            const float* __restrict__ W2, const float* __restrict__ b2,
                            const float* __restrict__ Wfc, const float* __restrict__ bfc,
                            float* __restrict__ Wc) {
    int t = threadIdx.x;
    if (blockIdx.x < 32) {
        int idx = blockIdx.x * 256 + t;
        int kc = idx >> 9, lane = (idx >> 3) & 63, i = idx & 7;
        int k = kc * 32 + (lane >> 4) * 8 + i;
        int j = lane & 15;
        W1B[idx] = f2bf(W1[k * NH + j]);
    } else {
        if (t < NH * NCLS) {
            int j = t / NCLS, c = t % NCLS;
            float acc = 0.0f;
            for (int k = 0; k < F_OUT; ++k) acc += W2[j * F_OUT + k] * Wfc[k * NCLS + c];
            Wc[t] = acc;
        } else if (t < NH * NCLS + NCLS) {
            int c = t - NH * NCLS;
            float acc = bfc[c];
            for (int k = 0; k < F_OUT; ++k) acc += b2[k] * Wfc[k * NCLS + c];
            Wc[t] = acc;
        }
    }
}

// ---------------- FUSED: blocks [0,NBIN) bin edges; [NBIN, NBIN+GEMM_BLOCKS) GEMM1 ----------------
// GEMM1 writes h1raw = bf16(feat @ W1) WITHOUT norm_src (applied per-edge in agg1).
// GEMM branch batches all 32 dwordx4 loads of a tile into registers before the MFMA
// chain -> 32 loads in flight per wave (round-3 counters: VGPR=48 killed MLP, 1.6 TB/s).
__global__ __launch_bounds__(256, 2) void fused_bin_gemm(const int* __restrict__ src,
                                                         const int* __restrict__ dst,
                                                         int* __restrict__ deg_out,
                                                         int* __restrict__ gcursor,
                                                         int* __restrict__ pairbuf,
                                                         const float* __restrict__ feat,
                                                         const unsigned short* __restrict__ W1B,
                                                         unsigned short* __restrict__ h1b) {
    __shared__ int hist[NB];
    __shared__ int cur[NB];
    int t = threadIdx.x;
    if (blockIdx.x < NBIN) {
        for (int i = t; i < NB; i += 256) hist[i] = 0;
        __syncthreads();
        int e0 = blockIdx.x * CHUNK;
        int nE = N_EDGES - e0; if (nE > CHUNK) nE = CHUNK;   // always multiple of 4
        for (int i = 4 * t; i < nE; i += 1024) {
            int4 sv = *(const int4*)(src + e0 + i);
            int4 dv = *(const int4*)(dst + e0 + i);
            atomicAdd(&deg_out[sv.x], 1); atomicAdd(&deg_out[sv.y], 1);
            atomicAdd(&deg_out[sv.z], 1); atomicAdd(&deg_out[sv.w], 1);
            atomicAdd(&hist[dv.x >> 7], 1); atomicAdd(&hist[dv.y >> 7], 1);
            atomicAdd(&hist[dv.z >> 7], 1); atomicAdd(&hist[dv.w >> 7], 1);
        }
        __syncthreads();
        int rot = blockIdx.x % NB;
        for (int j = t; j < NB; j += 256) {
            int b = j + rot; if (b >= NB) b -= NB;
            int h = hist[b];
            cur[b] = (h > 0) ? atomicAdd(&gcursor[b], h) : 0;
        }
        __syncthreads();
        for (int i = 4 * t; i < nE; i += 1024) {
            int4 sv = *(const int4*)(src + e0 + i);
            int4 dv = *(const int4*)(dst + e0 + i);
            int ss[4] = {sv.x, sv.y, sv.z, sv.w};
            int dd[4] = {dv.x, dv.y, dv.z, dv.w};
#pragma unroll
            for (int k = 0; k < 4; ++k) {
                int bb = dd[k] >> 7;
                int pos = atomicAdd(&cur[bb], 1);
                if (pos < BCAP) pairbuf[bb * BCAP + pos] = ss[k] | ((dd[k] & 127) << 17);
            }
        }
    } else {
        int lane = t & 63;
        int m = lane & 15;
        int q = lane >> 4;
        const s16x8* wb = (const s16x8*)W1B;
        s16x8 B[16];
#pragma unroll
        for (int kc = 0; kc < 16; ++kc) B[kc] = wb[kc * 64 + lane];
        int w = (blockIdx.x - NBIN) * 4 + (t >> 6);
        int nwaves = GEMM_BLOCKS * 4;
        const int ntiles = N_NODES / 16;   // 6250
        for (int tile = w; tile < ntiles; tile += nwaves) {
            const float* arow = feat + (size_t)(tile * 16 + m) * F_IN + q * 8;
            f32x4 va[16], vb[16];
#pragma unroll
            for (int kc = 0; kc < 16; ++kc) {
                va[kc] = *(const f32x4*)(arow + kc * 32);
                vb[kc] = *(const f32x4*)(arow + kc * 32 + 4);
            }
            f32x4 acc = {0.0f, 0.0f, 0.0f, 0.0f};
#pragma unroll
            for (int kc = 0; kc < 16; ++kc) {
                s16x8 a;
                a[0] = f2bf(va[kc].x); a[1] = f2bf(va[kc].y);
                a[2] = f2bf(va[kc].z); a[3] = f2bf(va[kc].w);
                a[4] = f2bf(vb[kc].x); a[5] = f2bf(vb[kc].y);
                a[6] = f2bf(vb[kc].z); a[7] = f2bf(vb[kc].w);
                acc = __builtin_amdgcn_mfma_f32_16x16x32_bf16(a, B[kc], acc, 0, 0, 0);
            }
#pragma unroll
            for (int r = 0; r < 4; ++r) {
                int node = tile * 16 + q * 4 + r;
                h1b[(size_t)node * NH + m] = f2bf(acc[r]);
            }
        }
    }
}

// ---------------- per-bucket CSR build (inline base-scan) + row_ptr + norms ----------------
__global__ __launch_bounds__(256) void bucket_csr_kernel(const int* __restrict__ gcursor,
                                                         const int* __restrict__ pairbuf,
                                                         const int* __restrict__ deg_out,
                                                         int* __restrict__ col,
                                                         int* __restrict__ row_ptr,
                                                         float* __restrict__ norm_dst,
                                                         float* __restrict__ norm_src) {
    __shared__ int hist[128];
    __shared__ int scn[128];
    __shared__ int red[256];
    int b = blockIdx.x;
    int t = threadIdx.x;
    if (t < 128) hist[t] = 0;
    // inline exclusive scan: gbase = sum_{i<b} min(gcursor[i], BCAP)
    int part = 0;
    for (int i = t; i < b; i += 256) {
        int v = gcursor[i]; if (v > BCAP) v = BCAP;
        part += v;
    }
    red[t] = part;
    __syncthreads();
    for (int off = 128; off > 0; off >>= 1) {
        if (t < off) red[t] += red[t + off];
        __syncthreads();
    }
    int gbase = red[0];
    int c = gcursor[b]; if (c > BCAP) c = BCAP;
    const int* pb = pairbuf + (size_t)b * BCAP;
    int pk[19], rk[19];
#pragma unroll
    for (int it = 0; it < 19; ++it) {
        int i = t + it * 256;
        bool valid = i < c;
        int v = valid ? pb[i] : 0;
        pk[it] = v;
        rk[it] = valid ? atomicAdd(&hist[v >> 17], 1) : 0;
    }
    __syncthreads();
    if (t < 128) scn[t] = hist[t];
    __syncthreads();
    for (int off = 1; off < 128; off <<= 1) {
        int x = (t >= off && t < 128) ? scn[t - off] : 0;
        __syncthreads();
        if (t < 128) scn[t] += x;   // inclusive
        __syncthreads();
    }
#pragma unroll
    for (int it = 0; it < 19; ++it) {
        int i = t + it * 256;
        if (i < c) {
            int v = pk[it];
            int node = v >> 17;
            int pos = gbase + (scn[node] - hist[node]) + rk[it];
            col[pos] = v & 0x1FFFF;
        }
    }
    int node = b * 128 + t;
    if (t < 128 && node < N_NODES) {
        row_ptr[node] = gbase + scn[t] - hist[t];
        norm_dst[node] = rsqrtf(fmaxf((float)hist[t], 1.0f));
        norm_src[node] = rsqrtf(fmaxf((float)deg_out[node], 1.0f));
    }
    if (b == NB - 1 && t == 0) row_ptr[N_NODES] = gbase + c;
}

// ---------------- AGG1: x1nb = bf16(relu(nd * sum ns[s]*h1raw[src] + b1) * ns[n]) ----------------
// wave-per-node; 2 lanes x ushort8(16B) per edge row, 32 edges in flight.
__global__ __launch_bounds__(256) void agg1_kernel(const int* __restrict__ row_ptr,
                                                   const int* __restrict__ col,
                                                   const unsigned short* __restrict__ h1b,
                                                   const float* __restrict__ norm_dst,
                                                   const float* __restrict__ norm_src,
                                                   const float* __restrict__ b1,
                                                   unsigned short* __restrict__ x1nb) {
    int t = threadIdx.x;
    int lane = t & 63;
    int n = blockIdx.x * 4 + (t >> 6);
    int eo = lane >> 1, half = lane & 1;
    int beg = row_ptr[n], end = row_ptr[n + 1];
    float acc[8] = {0.0f, 0.0f, 0.0f, 0.0f, 0.0f, 0.0f, 0.0f, 0.0f};
    for (int e = beg + eo; e < end; e += 32) {
        int s = col[e];
        float ns = norm_src[s];                       // 2 lanes same addr -> broadcast
        u16x8 hv = *(const u16x8*)(h1b + (size_t)s * NH + half * 8);
#pragma unroll
        for (int j = 0; j < 8; ++j) acc[j] += ns * bf2f(hv[j]);
    }
#pragma unroll
    for (int sh = 2; sh <= 32; sh <<= 1) {
#pragma unroll
        for (int j = 0; j < 8; ++j) acc[j] += __shfl_xor(acc[j], sh);
    }
    if (lane < 2) {
        float nd = norm_dst[n];
        float nsn = norm_src[n];
        u16x8 o;
#pragma unroll
        for (int j = 0; j < 8; ++j) {
            float v = acc[j] * nd + b1[half * 8 + j];
            o[j] = f2bf(fmaxf(v, 0.0f) * nsn);
        }
        *(u16x8*)(x1nb + (size_t)n * NH + half * 8) = o;
    }
}

// ---------------- AGG2 + tail: out = nd * (sum x1n[src]) @ Wc + bc ----------------
__global__ __launch_bounds__(256) void agg2_kernel(const int* __restrict__ row_ptr,
                                                   const int* __restrict__ col,
                                                   const unsigned short* __restrict__ x1nb,
                                                   const float* __restrict__ norm_dst,
                                                   const float* __restrict__ Wc,
                                                   float* __restrict__ out) {
    __shared__ float Wcs[NH * NCLS + NCLS];
    int t = threadIdx.x;
    if (t < NH * NCLS + NCLS) Wcs[t] = Wc[t];
    __syncthreads();
    int lane = t & 63;
    int n = blockIdx.x * 4 + (t >> 6);
    int eo = lane >> 1, half = lane & 1;
    int beg = row_ptr[n], end = row_ptr[n + 1];
    float acc[8] = {0.0f, 0.0f, 0.0f, 0.0f, 0.0f, 0.0f, 0.0f, 0.0f};
    for (int e = beg + eo; e < end; e += 32) {
        int s = col[e];
        u16x8 hv = *(const u16x8*)(x1nb + (size_t)s * NH + half * 8);
#pragma unroll
        for (int j = 0; j < 8; ++j) acc[j] += bf2f(hv[j]);
    }
#pragma unroll
    for (int sh = 2; sh <= 32; sh <<= 1) {
#pragma unroll
        for (int j = 0; j < 8; ++j) acc[j] += __shfl_xor(acc[j], sh);
    }
    float p0 = 0.0f, p1 = 0.0f, p2 = 0.0f;
    if (lane < 2) {
#pragma unroll
        for (int j = 0; j < 8; ++j) {
            float y = acc[j];
            int jj = half * 8 + j;
            p0 += y * Wcs[jj * NCLS + 0];
            p1 += y * Wcs[jj * NCLS + 1];
            p2 += y * Wcs[jj * NCLS + 2];
        }
    }
    p0 += __shfl_xor(p0, 1);
    p1 += __shfl_xor(p1, 1);
    p2 += __shfl_xor(p2, 1);
    if (lane == 0) {
        float nd = norm_dst[n];
        out[(size_t)n * NCLS + 0] = nd * p0 + Wcs[NH * NCLS + 0];
        out[(size_t)n * NCLS + 1] = nd * p1 + Wcs[NH * NCLS + 1];
        out[(size_t)n * NCLS + 2] = nd * p2 + Wcs[NH * NCLS + 2];
    }
}

// ---------------- launch ----------------
extern "C" void kernel_launch(void* const* d_in, const int* in_sizes, int n_in,
                              void* d_out, int out_size, void* d_ws, size_t ws_size,
                              hipStream_t stream) {
    const float* feat = (const float*)d_in[0];
    const int*   src  = (const int*)d_in[1];
    const int*   dst  = (const int*)d_in[2];
    const float* W1   = (const float*)d_in[3];
    const float* b1   = (const float*)d_in[4];
    const float* W2   = (const float*)d_in[5];
    const float* b2   = (const float*)d_in[6];
    const float* Wfc  = (const float*)d_in[7];
    const float* bfc  = (const float*)d_in[8];
    float* out = (float*)d_out;

    char* ws = (char*)d_ws;
    size_t off = 0;
    auto carve = [&](size_t bytes) {
        char* p = ws + off;
        off = (off + bytes + 255) & ~(size_t)255;
        return p;
    };
    int*   deg_out  = (int*)carve((size_t)N_NODES * 4);
    int*   gcursor  = (int*)carve((size_t)NB * 4);
    int*   pairbuf  = (int*)carve((size_t)NB * BCAP * 4);
    int*   row_ptr  = (int*)carve((size_t)(N_NODES + 1) * 4);
    int*   col      = (int*)carve((size_t)N_EDGES * 4);
    float* norm_dst = (float*)carve((size_t)N_NODES * 4);
    float* norm_src = (float*)carve((size_t)N_NODES * 4);
    unsigned short* h1b  = (unsigned short*)carve((size_t)N_NODES * NH * 2);
    unsigned short* x1nb = (unsigned short*)carve((size_t)N_NODES * NH * 2);
    unsigned short* W1B  = (unsigned short*)carve(16 * 64 * 8 * 2);
    float* Wc       = (float*)carve((NH * NCLS + NCLS) * 4);
    (void)ws_size;

    hipMemsetAsync(deg_out, 0, (size_t)N_NODES * 4, stream);
    hipMemsetAsync(gcursor, 0, (size_t)NB * 4, stream);

    prep_kernel<<<33, 256, 0, stream>>>(W1, W1B, W2, b2, Wfc, bfc, Wc);

    fused_bin_gemm<<<NBIN + GEMM_BLOCKS, 256, 0, stream>>>(src, dst, deg_out, gcursor,
                                                           pairbuf, feat, W1B, h1b);

    bucket_csr_kernel<<<NB, 256, 0, stream>>>(gcursor, pairbuf, deg_out,
                                              col, row_ptr, norm_dst, norm_src);

    agg1_kernel<<<N_NODES / 4, 256, 0, stream>>>(row_ptr, col, h1b, norm_dst, norm_src, b1, x1nb);

    agg2_kernel<<<N_NODES / 4, 256, 0, stream>>>(row_ptr, col, x1nb, norm_dst, Wc, out);
}